// Round 7
// baseline (361.712 us; speedup 1.0000x reference)
//
#include <hip/hip_runtime.h>

typedef _Float16 f16;
typedef f16 f16x8 __attribute__((ext_vector_type(8)));
typedef float f32x4 __attribute__((ext_vector_type(4)));

#define B_ 4
#define S_ 2048
#define D_ 1024
#define I_ 512
#define E_ 16
#define K_ 4
#define TPB_ 8192      /* S_*K_ entries per batch */
#define EROWS_ 2048    /* B_*T rows per expert */

// ---------------- async global->LDS (16B per lane, wave-uniform LDS base) ----
__device__ __forceinline__ void gload16(const void* g, void* l) {
    __builtin_amdgcn_global_load_lds(
        (const __attribute__((address_space(1))) void*)g,
        (__attribute__((address_space(3))) void*)l, 16, 0, 0);
}

// XCD-chunked bijective swizzle (grid % 8 == 0)
__device__ __forceinline__ int xcd_swz(int bid, int nwg) {
    int cpx = nwg >> 3;
    return (bid & 7) * cpx + (bid >> 3);
}

// ---------------- fp32 -> fp16 conversion ------------------------------------
__device__ __forceinline__ void cvt8(const float* __restrict__ s, f16* __restrict__ d, int i) {
    const float4* sp = (const float4*)s;
    float4 a = sp[2 * i], b = sp[2 * i + 1];
    f16x8 v;
    v[0] = (f16)a.x; v[1] = (f16)a.y; v[2] = (f16)a.z; v[3] = (f16)a.w;
    v[4] = (f16)b.x; v[5] = (f16)b.y; v[6] = (f16)b.z; v[7] = (f16)b.w;
    *(f16x8*)(d + (size_t)i * 8) = v;
}

__global__ void k_convert(const float* __restrict__ x, const float* __restrict__ w1,
                          const float* __restrict__ w3, const float* __restrict__ w2,
                          f16* __restrict__ xh, f16* __restrict__ w1h,
                          f16* __restrict__ w3h, f16* __restrict__ w2h) {
    const int N8 = (B_ * S_ * D_) / 8;
    int stride = gridDim.x * blockDim.x;
    for (int i = blockIdx.x * blockDim.x + threadIdx.x; i < N8; i += stride) {
        cvt8(x, xh, i);
        cvt8(w1, w1h, i);
        cvt8(w3, w3h, i);
        cvt8(w2, w2h, i);
    }
}

// ---------------- router: fp32 logits, softmax, top-4 ------------------------
__global__ void k_router(const float* __restrict__ x, const float* __restrict__ rw,
                         int* __restrict__ sel, float* __restrict__ ts) {
    int w = threadIdx.x >> 6, lane = threadIdx.x & 63;
    int tok = blockIdx.x * 4 + w;
    const float4* xp = (const float4*)(x + (size_t)tok * D_);
    float xr[16];
    #pragma unroll
    for (int j = 0; j < 4; ++j) {
        float4 v = xp[lane * 4 + j];
        xr[j * 4 + 0] = v.x; xr[j * 4 + 1] = v.y; xr[j * 4 + 2] = v.z; xr[j * 4 + 3] = v.w;
    }
    float sc[E_];
    #pragma unroll
    for (int e = 0; e < E_; ++e) {
        const float4* wp = (const float4*)(rw + (size_t)e * D_);
        float a = 0.f;
        #pragma unroll
        for (int j = 0; j < 4; ++j) {
            float4 v = wp[lane * 4 + j];
            a += xr[j * 4 + 0] * v.x + xr[j * 4 + 1] * v.y + xr[j * 4 + 2] * v.z + xr[j * 4 + 3] * v.w;
        }
        #pragma unroll
        for (int off = 32; off; off >>= 1) a += __shfl_xor(a, off);
        sc[e] = a;
    }
    float mx = sc[0];
    #pragma unroll
    for (int e = 1; e < E_; ++e) mx = fmaxf(mx, sc[e]);
    float ex[E_]; float sum = 0.f;
    #pragma unroll
    for (int e = 0; e < E_; ++e) { ex[e] = __expf(sc[e] - mx); sum += ex[e]; }
    float inv = 1.f / sum;
    if (lane == 0) {
        unsigned usedMask = 0;
        #pragma unroll
        for (int k = 0; k < K_; ++k) {
            int bi = -1; float bv = -1e30f, bev = 0.f;
            #pragma unroll
            for (int e = 0; e < E_; ++e) {
                bool ok = !((usedMask >> e) & 1) && (sc[e] > bv);
                if (ok) { bv = sc[e]; bi = e; bev = ex[e]; }
            }
            usedMask |= 1u << bi;
            sel[(size_t)tok * K_ + k] = bi;
            ts[(size_t)tok * K_ + k] = bev * inv;
        }
    }
}

// ---------------- stable counting sort + inverse permutation -----------------
__global__ void k_sort(const int* __restrict__ sel, int* __restrict__ src_tok,
                       int* __restrict__ invp) {
    __shared__ int ssel[TPB_];
    __shared__ int scnt[E_];
    int b = blockIdx.x, tid = threadIdx.x;
    for (int i = 0; i < 8; ++i) ssel[i * 1024 + tid] = sel[(size_t)b * TPB_ + i * 1024 + tid];
    __syncthreads();
    int e = tid >> 6, lane = tid & 63;
    unsigned long long lm = (1ull << lane) - 1ull;
    int c = 0;
    for (int ch = 0; ch < 128; ++ch) {
        unsigned long long m = __ballot(ssel[ch * 64 + lane] == e);
        c += __popcll(m);
    }
    if (lane == 0) scnt[e] = c;
    __syncthreads();
    int run = 0;
    for (int i = 0; i < E_; ++i) run += (i < e) ? scnt[i] : 0;
    for (int ch = 0; ch < 128; ++ch) {
        int f = ch * 64 + lane;
        int s = ssel[f];
        unsigned long long m = __ballot(s == e);
        if (s == e) {
            int p = run + __popcll(m & lm);
            src_tok[(size_t)b * TPB_ + p] = f >> 2;
            invp[(size_t)b * TPB_ + f] = p;
        }
        run += __popcll(m);
    }
}

// =====================  counted-vmcnt pipeline helpers  ======================
#define PIPE_WAIT8()  asm volatile("s_waitcnt vmcnt(8)" ::: "memory")
#define PIPE_WAIT0()  asm volatile("s_waitcnt vmcnt(0)" ::: "memory")
#define PIPE_BAR()    do { __builtin_amdgcn_s_barrier(); __builtin_amdgcn_sched_barrier(0); } while (0)
#define PIPE_ENDBAR() do { __builtin_amdgcn_sched_barrier(0); __builtin_amdgcn_s_barrier(); } while (0)

// ---------------- GEMM1: h = silu(X w1^T + b1) * (X w3^T + b3) ---------------
// 256x128 tile, BK=64, 8 waves (4M x 2N), double-buffered LDS (128 KiB),
// counted vmcnt(8) keeps next tile's 8 global_load_lds in flight across MFMA.
__global__ __launch_bounds__(512, 1) void k_gemm1(
    const f16* __restrict__ xh, const f16* __restrict__ w1h, const f16* __restrict__ w3h,
    const float* __restrict__ b1, const float* __restrict__ b3,
    const int* __restrict__ src_tok, f16* __restrict__ h) {
    __shared__ f16 Als[2][256 * 64];
    __shared__ f16 B1s[2][128 * 64];
    __shared__ f16 B3s[2][128 * 64];
    int bid = xcd_swz(blockIdx.x, 512);
    int e = bid >> 5, rem = bid & 31, mb = rem >> 2, nb = rem & 3;
    int tid = threadIdx.x, lane = tid & 63, w = tid >> 6, wr = w >> 1, wc = w & 1;
    // wr in 0..3 (M), wc in 0..1 (N)

    int lr = lane >> 3;                 // row-within-8 staged by this lane
    int cswz = (lane & 7) ^ lr;         // pre-swizzled source chunk
    const f16* arow[4];
    int bofs[2];
    int ldsA[4], ldsB[2];
    #pragma unroll
    for (int i = 0; i < 4; ++i) {
        int r = i * 64 + w * 8 + lr;    // 0..255
        int re = mb * 256 + r;
        int bb = re >> 9;               // 256-tiles never straddle the 512 boundary
        int tokk = src_tok[bb * TPB_ + e * 512 + (re & 511)];
        arow[i] = xh + ((size_t)(bb * S_ + tokk)) * D_ + cswz * 8;
        ldsA[i] = (i * 64 + w * 8) * 64;  // wave-uniform
    }
    #pragma unroll
    for (int i = 0; i < 2; ++i) {
        int r = i * 64 + w * 8 + lr;    // 0..127
        bofs[i] = (e * I_ + nb * 128 + r) * D_ + cswz * 8;
        ldsB[i] = (i * 64 + w * 8) * 64;
    }

    f32x4 acc1[4][4], acc3[4][4];
    const f32x4 fz = {0.f, 0.f, 0.f, 0.f};
    #pragma unroll
    for (int m = 0; m < 4; ++m)
        #pragma unroll
        for (int n = 0; n < 4; ++n) { acc1[m][n] = fz; acc3[m][n] = fz; }

#define STAGE1(t, bsel) do { int ko_ = (t) * 64;                                   \
    _Pragma("unroll") for (int i_ = 0; i_ < 4; ++i_)                               \
        gload16(arow[i_] + ko_, &Als[bsel][ldsA[i_]]);                             \
    _Pragma("unroll") for (int i_ = 0; i_ < 2; ++i_) {                             \
        gload16(w1h + bofs[i_] + ko_, &B1s[bsel][ldsB[i_]]);                       \
        gload16(w3h + bofs[i_] + ko_, &B3s[bsel][ldsB[i_]]); } } while (0)

#define COMPUTE1(bsel)                                                             \
    _Pragma("unroll") for (int kk = 0; kk < 2; ++kk) {                             \
        f16x8 af[4], bf1[4], bf3[4];                                               \
        int kb = kk * 32 + (lane >> 4) * 8;                                        \
        _Pragma("unroll") for (int m = 0; m < 4; ++m) {                            \
            int row = wr * 64 + m * 16 + (lane & 15);                              \
            af[m] = *(const f16x8*)&Als[bsel][row * 64 + (kb ^ ((row & 7) * 8))];  \
        }                                                                          \
        _Pragma("unroll") for (int n = 0; n < 4; ++n) {                            \
            int row = wc * 64 + n * 16 + (lane & 15);                              \
            int o = row * 64 + (kb ^ ((row & 7) * 8));                             \
            bf1[n] = *(const f16x8*)&B1s[bsel][o];                                 \
            bf3[n] = *(const f16x8*)&B3s[bsel][o];                                 \
        }                                                                          \
        _Pragma("unroll") for (int m = 0; m < 4; ++m)                              \
            _Pragma("unroll") for (int n = 0; n < 4; ++n) {                        \
                acc1[m][n] = __builtin_amdgcn_mfma_f32_16x16x32_f16(af[m], bf1[n], acc1[m][n], 0, 0, 0); \
                acc3[m][n] = __builtin_amdgcn_mfma_f32_16x16x32_f16(af[m], bf3[n], acc3[m][n], 0, 0, 0); \
            }                                                                      \
    }

    STAGE1(0, 0);                       // 8 loads in flight
    for (int t = 0; t < 15; ++t) {
        STAGE1(t + 1, (t + 1) & 1);     // +8 -> 16 in flight
        PIPE_WAIT8();                   // drain tile t's 8; keep t+1's flying
        PIPE_BAR();
        COMPUTE1(t & 1);
        PIPE_ENDBAR();
    }
    PIPE_WAIT0();
    PIPE_BAR();
    COMPUTE1(1);                        // t = 15 (odd buffer)

    // epilogue: bias + silu*gate, write h (fp16)
    int icb = nb * 128 + wc * 64;
    float bias1[4], bias3[4];
    #pragma unroll
    for (int n = 0; n < 4; ++n) {
        int ic = icb + n * 16 + (lane & 15);
        bias1[n] = b1[e * I_ + ic];
        bias3[n] = b3[e * I_ + ic];
    }
    #pragma unroll
    for (int m = 0; m < 4; ++m)
        #pragma unroll
        for (int n = 0; n < 4; ++n) {
            int col = icb + n * 16 + (lane & 15);
            #pragma unroll
            for (int r = 0; r < 4; ++r) {
                float z1 = acc1[m][n][r] + bias1[n];
                float z3 = acc3[m][n][r] + bias3[n];
                float sv = z1 / (1.f + __expf(-z1));
                float hv = sv * z3;
                int row = mb * 256 + wr * 64 + m * 16 + (lane >> 4) * 4 + r;
                h[((size_t)e * EROWS_ + row) * I_ + col] = (f16)hv;
            }
        }
#undef STAGE1
#undef COMPUTE1
}

// ---------------- GEMM2 (combine path): h2p = h w2^T + b2 (dispatch order) ---
// 128x128 tile, 4 waves, double-buffered LDS (64 KiB), counted vmcnt(8).
__global__ __launch_bounds__(256, 2) void k_gemm2(
    const f16* __restrict__ h, const f16* __restrict__ w2h, const float* __restrict__ b2,
    f16* __restrict__ h2p) {
    __shared__ f16 Als[2][128 * 64];
    __shared__ f16 Bs[2][128 * 64];
    int bid = xcd_swz(blockIdx.x, 2048);
    int e = bid >> 7, rem = bid & 127, mb = rem >> 3, nb = rem & 7;
    int tid = threadIdx.x, lane = tid & 63, w = tid >> 6, wr = w >> 1, wc = w & 1;

    int lr = lane >> 3;
    int cswz = (lane & 7) ^ lr;
    size_t aofs[4], bofs[4];
    int ldsO[4];
    #pragma unroll
    for (int i = 0; i < 4; ++i) {
        int r = w * 32 + i * 8 + lr;
        aofs[i] = ((size_t)e * EROWS_ + mb * 128 + r) * I_ + cswz * 8;
        bofs[i] = ((size_t)e * D_ + nb * 128 + r) * I_ + cswz * 8;
        ldsO[i] = w * 2048 + i * 512;
    }

    f32x4 acc[4][4];
    const f32x4 fz = {0.f, 0.f, 0.f, 0.f};
    #pragma unroll
    for (int m = 0; m < 4; ++m)
        #pragma unroll
        for (int n = 0; n < 4; ++n) acc[m][n] = fz;

#define STAGE2(t, bsel) do { int ko_ = (t) * 64;                                   \
    _Pragma("unroll") for (int i_ = 0; i_ < 4; ++i_) {                             \
        gload16(h + aofs[i_] + ko_, &Als[bsel][ldsO[i_]]);                         \
        gload16(w2h + bofs[i_] + ko_, &Bs[bsel][ldsO[i_]]); } } while (0)

#define COMPUTE2(bsel)                                                             \
    _Pragma("unroll") for (int kk = 0; kk < 2; ++kk) {                             \
        f16x8 af[4], bf[4];                                                        \
        int kb = kk * 32 + (lane >> 4) * 8;                                        \
        _Pragma("unroll") for (int m = 0; m < 4; ++m) {                            \
            int row = wr * 64 + m * 16 + (lane & 15);                              \
            af[m] = *(const f16x8*)&Als[bsel][row * 64 + (kb ^ ((row & 7) * 8))];  \
        }                                                                          \
        _Pragma("unroll") for (int n = 0; n < 4; ++n) {                            \
            int row = wc * 64 + n * 16 + (lane & 15);                              \
            bf[n] = *(const f16x8*)&Bs[bsel][row * 64 + (kb ^ ((row & 7) * 8))];   \
        }                                                                          \
        _Pragma("unroll") for (int m = 0; m < 4; ++m)                              \
            _Pragma("unroll") for (int n = 0; n < 4; ++n)                          \
                acc[m][n] = __builtin_amdgcn_mfma_f32_16x16x32_f16(af[m], bf[n], acc[m][n], 0, 0, 0); \
    }

    STAGE2(0, 0);
    for (int t = 0; t < 7; ++t) {
        STAGE2(t + 1, (t + 1) & 1);
        PIPE_WAIT8();
        PIPE_BAR();
        COMPUTE2(t & 1);
        PIPE_ENDBAR();
    }
    PIPE_WAIT0();
    PIPE_BAR();
    COMPUTE2(1);                        // t = 7 (odd buffer)

    int dcb = nb * 128 + wc * 64;
    float bias[4];
    #pragma unroll
    for (int n = 0; n < 4; ++n) bias[n] = b2[e * D_ + dcb + n * 16 + (lane & 15)];
    #pragma unroll
    for (int m = 0; m < 4; ++m)
        #pragma unroll
        for (int r = 0; r < 4; ++r) {
            int row = mb * 128 + wr * 64 + m * 16 + (lane >> 4) * 4 + r;
            #pragma unroll
            for (int n = 0; n < 4; ++n) {
                int col = dcb + n * 16 + (lane & 15);
                h2p[((size_t)e * EROWS_ + row) * D_ + col] = (f16)(acc[m][n][r] + bias[n]);
            }
        }
#undef STAGE2
#undef COMPUTE2
}

// ---------------- GEMM2 (atomic fallback, ws too small) ----------------------
__global__ __launch_bounds__(256, 2) void k_gemm2_atomic(
    const f16* __restrict__ h, const f16* __restrict__ w2h, const float* __restrict__ b2,
    const int* __restrict__ src_tok, const int* __restrict__ invp,
    const float* __restrict__ ts, float* __restrict__ out) {
    __shared__ f16 Als[128 * 64];
    __shared__ f16 Bs[128 * 64];
    int bid = xcd_swz(blockIdx.x, 2048);
    int e = bid >> 7, rem = bid & 127, mb = rem >> 3, nb = rem & 7;
    int tid = threadIdx.x, lane = tid & 63, w = tid >> 6, wr = w >> 1, wc = w & 1;

    int lr = lane >> 3;
    int cswz = (lane & 7) ^ lr;
    size_t aofs[4], bofs[4];
    int ldsA[4];
    #pragma unroll
    for (int i = 0; i < 4; ++i) {
        int r = w * 32 + i * 8 + lr;
        aofs[i] = ((size_t)e * EROWS_ + mb * 128 + r) * I_ + cswz * 8;
        bofs[i] = ((size_t)e * D_ + nb * 128 + r) * I_ + cswz * 8;
        ldsA[i] = w * 2048 + i * 512;
    }
    f32x4 acc[4][4];
    const f32x4 fz = {0.f, 0.f, 0.f, 0.f};
    #pragma unroll
    for (int m = 0; m < 4; ++m)
        #pragma unroll
        for (int n = 0; n < 4; ++n) acc[m][n] = fz;
    for (int ks = 0; ks < 8; ++ks) {
        __syncthreads();
        int ko = ks * 64;
        #pragma unroll
        for (int i = 0; i < 4; ++i) {
            gload16(h + aofs[i] + ko, &Als[ldsA[i]]);
            gload16(w2h + bofs[i] + ko, &Bs[ldsA[i]]);
        }
        __syncthreads();
        #pragma unroll
        for (int kk = 0; kk < 2; ++kk) {
            f16x8 af[4], bf[4];
            int kb = kk * 32 + (lane >> 4) * 8;
            #pragma unroll
            for (int m = 0; m < 4; ++m) {
                int row = wr * 64 + m * 16 + (lane & 15);
                af[m] = *(const f16x8*)&Als[row * 64 + (kb ^ ((row & 7) * 8))];
            }
            #pragma unroll
            for (int n = 0; n < 4; ++n) {
                int row = wc * 64 + n * 16 + (lane & 15);
                bf[n] = *(const f16x8*)&Bs[row * 64 + (kb ^ ((row & 7) * 8))];
            }
            #pragma unroll
            for (int m = 0; m < 4; ++m)
                #pragma unroll
                for (int n = 0; n < 4; ++n)
                    acc[m][n] = __builtin_amdgcn_mfma_f32_16x16x32_f16(af[m], bf[n], acc[m][n], 0, 0, 0);
        }
    }
    int dcb = nb * 128 + wc * 64;
    float bias[4];
    #pragma unroll
    for (int n = 0; n < 4; ++n) bias[n] = b2[e * D_ + dcb + n * 16 + (lane & 15)];
    #pragma unroll
    for (int m = 0; m < 4; ++m)
        #pragma unroll
        for (int r = 0; r < 4; ++r) {
            int re = mb * 128 + wr * 64 + m * 16 + (lane >> 4) * 4 + r;
            int bb = re >> 9;
            int pos = bb * TPB_ + e * 512 + (re & 511);
            int tokk = src_tok[pos];
            float g = 0.f;
            #pragma unroll
            for (int k = 0; k < K_; ++k)
                if (invp[bb * TPB_ + tokk * K_ + k] == e * 512 + (re & 511))
                    g = ts[bb * TPB_ + tokk * K_ + k];
            float* op = out + ((size_t)(bb * S_ + tokk)) * D_;
            #pragma unroll
            for (int n = 0; n < 4; ++n) {
                int col = dcb + n * 16 + (lane & 15);
                atomicAdd(op + col, g * (acc[m][n][r] + bias[n]));
            }
        }
}

// ---------------- combine: out[b,s,:] = sum_k ts * h2p[pos(b,s,k)] -----------
__global__ __launch_bounds__(256) void k_combine(
    const f16* __restrict__ h2p, const float* __restrict__ ts,
    const int* __restrict__ invp, float* __restrict__ out) {
    int w = threadIdx.x >> 6, lane = threadIdx.x & 63;
    int t = blockIdx.x * 4 + w;
    int b = t >> 11, s = t & 2047;
    int base = b * TPB_ + s * 4;
    float g[4]; const f16* rows[4];
    #pragma unroll
    for (int k = 0; k < 4; ++k) {
        int p = invp[base + k];
        g[k] = ts[base + k];
        int e = p >> 9, n = (b << 9) + (p & 511);
        rows[k] = h2p + ((size_t)(e * EROWS_ + n)) * D_;
    }
    float* op = out + (size_t)t * D_;
    #pragma unroll
    for (int c = 0; c < 2; ++c) {
        int d = c * 512 + lane * 8;
        float a[8] = {0.f};
        #pragma unroll
        for (int k = 0; k < 4; ++k) {
            f16x8 v = *(const f16x8*)(rows[k] + d);
            #pragma unroll
            for (int j = 0; j < 8; ++j) a[j] += g[k] * (float)v[j];
        }
        *(float4*)(op + d)     = make_float4(a[0], a[1], a[2], a[3]);
        *(float4*)(op + d + 4) = make_float4(a[4], a[5], a[6], a[7]);
    }
}

// ---------------- launch -----------------------------------------------------
extern "C" void kernel_launch(void* const* d_in, const int* in_sizes, int n_in,
                              void* d_out, int out_size, void* d_ws, size_t ws_size,
                              hipStream_t stream) {
    const float* x  = (const float*)d_in[0];
    const float* rw = (const float*)d_in[1];
    const float* w1 = (const float*)d_in[2];
    const float* b1 = (const float*)d_in[3];
    const float* w2 = (const float*)d_in[4];
    const float* b2 = (const float*)d_in[5];
    const float* w3 = (const float*)d_in[6];
    const float* b3 = (const float*)d_in[7];
    float* out = (float*)d_out;

    const size_t NEL = (size_t)B_ * S_ * D_;
    char* p = (char*)d_ws;
    f16* xh  = (f16*)p; p += NEL * 2;
    f16* w1h = (f16*)p; p += NEL * 2;
    f16* w3h = (f16*)p; p += NEL * 2;
    f16* w2h = (f16*)p; p += NEL * 2;
    f16* h   = (f16*)p; p += (size_t)E_ * EROWS_ * I_ * 2;
    int*   sel     = (int*)p;   p += (size_t)B_ * TPB_ * 4;
    float* ts      = (float*)p; p += (size_t)B_ * TPB_ * 4;
    int*   src_tok = (int*)p;   p += (size_t)B_ * TPB_ * 4;
    int*   invp    = (int*)p;   p += (size_t)B_ * TPB_ * 4;
    f16* h2p = (f16*)p; p += (size_t)E_ * EROWS_ * D_ * 2;
    size_t need = (size_t)(p - (char*)d_ws);

    k_convert<<<2048, 256, 0, stream>>>(x, w1, w3, w2, xh, w1h, w3h, w2h);
    k_router<<<2048, 256, 0, stream>>>(x, rw, sel, ts);
    k_sort<<<4, 1024, 0, stream>>>(sel, src_tok, invp);
    k_gemm1<<<512, 512, 0, stream>>>(xh, w1h, w3h, b1, b3, src_tok, h);
    if (ws_size >= need) {
        k_gemm2<<<2048, 256, 0, stream>>>(h, w2h, b2, h2p);
        k_combine<<<2048, 256, 0, stream>>>(h2p, ts, invp, out);
    } else {
        hipMemsetAsync(d_out, 0, (size_t)out_size * sizeof(float), stream);
        k_gemm2_atomic<<<2048, 256, 0, stream>>>(h, w2h, b2, src_tok, invp, ts, out);
    }
}

// Round 8
// 354.237 us; speedup vs baseline: 1.0211x; 1.0211x over previous
//
#include <hip/hip_runtime.h>

typedef _Float16 f16;
typedef f16 f16x8 __attribute__((ext_vector_type(8)));
typedef float f32x4 __attribute__((ext_vector_type(4)));

#define B_ 4
#define S_ 2048
#define D_ 1024
#define I_ 512
#define E_ 16
#define K_ 4
#define TPB_ 8192      /* S_*K_ entries per batch */
#define EROWS_ 2048    /* B_*T rows per expert */

// ---------------- async global->LDS (16B per lane, wave-uniform LDS base) ----
__device__ __forceinline__ void gload16(const void* g, void* l) {
    __builtin_amdgcn_global_load_lds(
        (const __attribute__((address_space(1))) void*)g,
        (__attribute__((address_space(3))) void*)l, 16, 0, 0);
}

// XCD-chunked bijective swizzle (grid % 8 == 0)
__device__ __forceinline__ int xcd_swz(int bid, int nwg) {
    int cpx = nwg >> 3;
    return (bid & 7) * cpx + (bid >> 3);
}

// ---------------- fp32 -> fp16 conversion (weights only; x handled in router)
__device__ __forceinline__ void cvt8(const float* __restrict__ s, f16* __restrict__ d, int i) {
    const float4* sp = (const float4*)s;
    float4 a = sp[2 * i], b = sp[2 * i + 1];
    f16x8 v;
    v[0] = (f16)a.x; v[1] = (f16)a.y; v[2] = (f16)a.z; v[3] = (f16)a.w;
    v[4] = (f16)b.x; v[5] = (f16)b.y; v[6] = (f16)b.z; v[7] = (f16)b.w;
    *(f16x8*)(d + (size_t)i * 8) = v;
}

__global__ void k_convert(const float* __restrict__ w1, const float* __restrict__ w3,
                          const float* __restrict__ w2,
                          f16* __restrict__ w1h, f16* __restrict__ w3h,
                          f16* __restrict__ w2h) {
    const int N8 = (E_ * I_ * D_) / 8;   // 1048576 groups of 8 per weight tensor
    int stride = gridDim.x * blockDim.x;
    for (int i = blockIdx.x * blockDim.x + threadIdx.x; i < N8; i += stride) {
        cvt8(w1, w1h, i);
        cvt8(w3, w3h, i);
        cvt8(w2, w2h, i);
    }
}

// ---------------- router: fp32 logits, softmax, top-4; also emits xh ---------
__global__ void k_router(const float* __restrict__ x, const float* __restrict__ rw,
                         f16* __restrict__ xh, int* __restrict__ sel,
                         float* __restrict__ ts) {
    int w = threadIdx.x >> 6, lane = threadIdx.x & 63;
    int tok = blockIdx.x * 4 + w;
    const float4* xp = (const float4*)(x + (size_t)tok * D_);
    float xr[16];
    #pragma unroll
    for (int j = 0; j < 4; ++j) {
        float4 v = xp[lane * 4 + j];
        xr[j * 4 + 0] = v.x; xr[j * 4 + 1] = v.y; xr[j * 4 + 2] = v.z; xr[j * 4 + 3] = v.w;
    }
    // fused fp32->fp16 conversion of this token row (lane holds elems lane*16..+15)
    {
        f16x8 v0, v1;
        #pragma unroll
        for (int j = 0; j < 8; ++j) { v0[j] = (f16)xr[j]; v1[j] = (f16)xr[8 + j]; }
        f16* xrow = xh + (size_t)tok * D_ + lane * 16;
        *(f16x8*)xrow = v0;
        *(f16x8*)(xrow + 8) = v1;
    }
    float sc[E_];
    #pragma unroll
    for (int e = 0; e < E_; ++e) {
        const float4* wp = (const float4*)(rw + (size_t)e * D_);
        float a = 0.f;
        #pragma unroll
        for (int j = 0; j < 4; ++j) {
            float4 v = wp[lane * 4 + j];
            a += xr[j * 4 + 0] * v.x + xr[j * 4 + 1] * v.y + xr[j * 4 + 2] * v.z + xr[j * 4 + 3] * v.w;
        }
        #pragma unroll
        for (int off = 32; off; off >>= 1) a += __shfl_xor(a, off);
        sc[e] = a;
    }
    float mx = sc[0];
    #pragma unroll
    for (int e = 1; e < E_; ++e) mx = fmaxf(mx, sc[e]);
    float ex[E_]; float sum = 0.f;
    #pragma unroll
    for (int e = 0; e < E_; ++e) { ex[e] = __expf(sc[e] - mx); sum += ex[e]; }
    float inv = 1.f / sum;
    if (lane == 0) {
        unsigned usedMask = 0;
        #pragma unroll
        for (int k = 0; k < K_; ++k) {
            int bi = -1; float bv = -1e30f, bev = 0.f;
            #pragma unroll
            for (int e = 0; e < E_; ++e) {
                bool ok = !((usedMask >> e) & 1) && (sc[e] > bv);
                if (ok) { bv = sc[e]; bi = e; bev = ex[e]; }
            }
            usedMask |= 1u << bi;
            sel[(size_t)tok * K_ + k] = bi;
            ts[(size_t)tok * K_ + k] = bev * inv;
        }
    }
}

// ---------------- stable counting sort + inverse permutation -----------------
__global__ void k_sort(const int* __restrict__ sel, int* __restrict__ src_tok,
                       int* __restrict__ invp) {
    __shared__ int ssel[TPB_];
    __shared__ int scnt[E_];
    int b = blockIdx.x, tid = threadIdx.x;
    for (int i = 0; i < 8; ++i) ssel[i * 1024 + tid] = sel[(size_t)b * TPB_ + i * 1024 + tid];
    __syncthreads();
    int e = tid >> 6, lane = tid & 63;
    unsigned long long lm = (1ull << lane) - 1ull;
    int c = 0;
    for (int ch = 0; ch < 128; ++ch) {
        unsigned long long m = __ballot(ssel[ch * 64 + lane] == e);
        c += __popcll(m);
    }
    if (lane == 0) scnt[e] = c;
    __syncthreads();
    int run = 0;
    for (int i = 0; i < E_; ++i) run += (i < e) ? scnt[i] : 0;
    for (int ch = 0; ch < 128; ++ch) {
        int f = ch * 64 + lane;
        int s = ssel[f];
        unsigned long long m = __ballot(s == e);
        if (s == e) {
            int p = run + __popcll(m & lm);
            src_tok[(size_t)b * TPB_ + p] = f >> 2;
            invp[(size_t)b * TPB_ + f] = p;
        }
        run += __popcll(m);
    }
}

// ---------------- GEMM1: h = silu(X w1^T + b1) * (X w3^T + b3) ---------------
// 128x128 tile, BK=64, 4 waves of 64x64; single-buffered (3 blocks/CU --
// inter-block overlap hides the barrier drain; measured 71 us / 968 TF).
__global__ __launch_bounds__(256, 2) void k_gemm1(
    const f16* __restrict__ xh, const f16* __restrict__ w1h, const f16* __restrict__ w3h,
    const float* __restrict__ b1, const float* __restrict__ b3,
    const int* __restrict__ src_tok, f16* __restrict__ h) {
    __shared__ f16 Als[128 * 64];
    __shared__ f16 B1s[128 * 64];
    __shared__ f16 B3s[128 * 64];
    int bid = xcd_swz(blockIdx.x, 1024);
    int e = bid >> 6, rem = bid & 63, mb = rem >> 2, nb = rem & 3;
    int tid = threadIdx.x, lane = tid & 63, w = tid >> 6, wr = w >> 1, wc = w & 1;

    int lr = lane >> 3;
    int cswz = (lane & 7) ^ lr;
    const f16* arow[4];
    int bofs[4];
    int ldsA[4];
    #pragma unroll
    for (int i = 0; i < 4; ++i) {
        int r = w * 32 + i * 8 + lr;
        int re = mb * 128 + r;
        int bb = re >> 9;
        int tokk = src_tok[bb * TPB_ + e * 512 + (re & 511)];
        arow[i] = xh + ((size_t)(bb * S_ + tokk)) * D_ + cswz * 8;
        int brw = nb * 128 + r;
        bofs[i] = (e * I_ + brw) * D_ + cswz * 8;
        ldsA[i] = w * 2048 + i * 512;
    }

    f32x4 acc1[4][4], acc3[4][4];
    const f32x4 fz = {0.f, 0.f, 0.f, 0.f};
    #pragma unroll
    for (int m = 0; m < 4; ++m)
        #pragma unroll
        for (int n = 0; n < 4; ++n) { acc1[m][n] = fz; acc3[m][n] = fz; }

    for (int ks = 0; ks < 16; ++ks) {
        __syncthreads();
        int ko = ks * 64;
        #pragma unroll
        for (int i = 0; i < 4; ++i) {
            gload16(arow[i] + ko, &Als[ldsA[i]]);
            gload16(w1h + bofs[i] + ko, &B1s[ldsA[i]]);
            gload16(w3h + bofs[i] + ko, &B3s[ldsA[i]]);
        }
        __syncthreads();
        #pragma unroll
        for (int kk = 0; kk < 2; ++kk) {
            f16x8 af[4], bf1[4], bf3[4];
            int kb = kk * 32 + (lane >> 4) * 8;
            #pragma unroll
            for (int m = 0; m < 4; ++m) {
                int row = wr * 64 + m * 16 + (lane & 15);
                af[m] = *(const f16x8*)&Als[row * 64 + (kb ^ ((row & 7) * 8))];
            }
            #pragma unroll
            for (int n = 0; n < 4; ++n) {
                int row = wc * 64 + n * 16 + (lane & 15);
                int o = row * 64 + (kb ^ ((row & 7) * 8));
                bf1[n] = *(const f16x8*)&B1s[o];
                bf3[n] = *(const f16x8*)&B3s[o];
            }
            #pragma unroll
            for (int m = 0; m < 4; ++m)
                #pragma unroll
                for (int n = 0; n < 4; ++n) {
                    acc1[m][n] = __builtin_amdgcn_mfma_f32_16x16x32_f16(af[m], bf1[n], acc1[m][n], 0, 0, 0);
                    acc3[m][n] = __builtin_amdgcn_mfma_f32_16x16x32_f16(af[m], bf3[n], acc3[m][n], 0, 0, 0);
                }
        }
    }
    int icb = nb * 128 + wc * 64;
    float bias1[4], bias3[4];
    #pragma unroll
    for (int n = 0; n < 4; ++n) {
        int ic = icb + n * 16 + (lane & 15);
        bias1[n] = b1[e * I_ + ic];
        bias3[n] = b3[e * I_ + ic];
    }
    #pragma unroll
    for (int m = 0; m < 4; ++m)
        #pragma unroll
        for (int n = 0; n < 4; ++n) {
            int col = icb + n * 16 + (lane & 15);
            #pragma unroll
            for (int r = 0; r < 4; ++r) {
                float z1 = acc1[m][n][r] + bias1[n];
                float z3 = acc3[m][n][r] + bias3[n];
                float sv = z1 / (1.f + __expf(-z1));
                float hv = sv * z3;
                int row = mb * 128 + wr * 64 + m * 16 + (lane >> 4) * 4 + r;
                h[((size_t)e * EROWS_ + row) * I_ + col] = (f16)hv;
            }
        }
}

// ---------------- GEMM2 (combine path): h2p = h w2^T + b2 (dispatch order) ---
__global__ __launch_bounds__(256, 2) void k_gemm2(
    const f16* __restrict__ h, const f16* __restrict__ w2h, const float* __restrict__ b2,
    f16* __restrict__ h2p) {
    __shared__ f16 Als[128 * 64];
    __shared__ f16 Bs[128 * 64];
    int bid = xcd_swz(blockIdx.x, 2048);
    int e = bid >> 7, rem = bid & 127, mb = rem >> 3, nb = rem & 7;
    int tid = threadIdx.x, lane = tid & 63, w = tid >> 6, wr = w >> 1, wc = w & 1;

    int lr = lane >> 3;
    int cswz = (lane & 7) ^ lr;
    size_t aofs[4], bofs[4];
    int ldsA[4];
    #pragma unroll
    for (int i = 0; i < 4; ++i) {
        int r = w * 32 + i * 8 + lr;
        aofs[i] = ((size_t)e * EROWS_ + mb * 128 + r) * I_ + cswz * 8;
        bofs[i] = ((size_t)e * D_ + nb * 128 + r) * I_ + cswz * 8;
        ldsA[i] = w * 2048 + i * 512;
    }

    f32x4 acc[4][4];
    const f32x4 fz = {0.f, 0.f, 0.f, 0.f};
    #pragma unroll
    for (int m = 0; m < 4; ++m)
        #pragma unroll
        for (int n = 0; n < 4; ++n) acc[m][n] = fz;

    for (int ks = 0; ks < 8; ++ks) {
        __syncthreads();
        int ko = ks * 64;
        #pragma unroll
        for (int i = 0; i < 4; ++i) {
            gload16(h + aofs[i] + ko, &Als[ldsA[i]]);
            gload16(w2h + bofs[i] + ko, &Bs[ldsA[i]]);
        }
        __syncthreads();
        #pragma unroll
        for (int kk = 0; kk < 2; ++kk) {
            f16x8 af[4], bf[4];
            int kb = kk * 32 + (lane >> 4) * 8;
            #pragma unroll
            for (int m = 0; m < 4; ++m) {
                int row = wr * 64 + m * 16 + (lane & 15);
                af[m] = *(const f16x8*)&Als[row * 64 + (kb ^ ((row & 7) * 8))];
            }
            #pragma unroll
            for (int n = 0; n < 4; ++n) {
                int row = wc * 64 + n * 16 + (lane & 15);
                bf[n] = *(const f16x8*)&Bs[row * 64 + (kb ^ ((row & 7) * 8))];
            }
            #pragma unroll
            for (int m = 0; m < 4; ++m)
                #pragma unroll
                for (int n = 0; n < 4; ++n)
                    acc[m][n] = __builtin_amdgcn_mfma_f32_16x16x32_f16(af[m], bf[n], acc[m][n], 0, 0, 0);
        }
    }
    int dcb = nb * 128 + wc * 64;
    float bias[4];
    #pragma unroll
    for (int n = 0; n < 4; ++n) bias[n] = b2[e * D_ + dcb + n * 16 + (lane & 15)];
    #pragma unroll
    for (int m = 0; m < 4; ++m)
        #pragma unroll
        for (int r = 0; r < 4; ++r) {
            int row = mb * 128 + wr * 64 + m * 16 + (lane >> 4) * 4 + r;
            #pragma unroll
            for (int n = 0; n < 4; ++n) {
                int col = dcb + n * 16 + (lane & 15);
                h2p[((size_t)e * EROWS_ + row) * D_ + col] = (f16)(acc[m][n][r] + bias[n]);
            }
        }
}

// ---------------- GEMM2 (atomic fallback, ws too small) ----------------------
__global__ __launch_bounds__(256, 2) void k_gemm2_atomic(
    const f16* __restrict__ h, const f16* __restrict__ w2h, const float* __restrict__ b2,
    const int* __restrict__ src_tok, const int* __restrict__ invp,
    const float* __restrict__ ts, float* __restrict__ out) {
    __shared__ f16 Als[128 * 64];
    __shared__ f16 Bs[128 * 64];
    int bid = xcd_swz(blockIdx.x, 2048);
    int e = bid >> 7, rem = bid & 127, mb = rem >> 3, nb = rem & 7;
    int tid = threadIdx.x, lane = tid & 63, w = tid >> 6, wr = w >> 1, wc = w & 1;

    int lr = lane >> 3;
    int cswz = (lane & 7) ^ lr;
    size_t aofs[4], bofs[4];
    int ldsA[4];
    #pragma unroll
    for (int i = 0; i < 4; ++i) {
        int r = w * 32 + i * 8 + lr;
        aofs[i] = ((size_t)e * EROWS_ + mb * 128 + r) * I_ + cswz * 8;
        bofs[i] = ((size_t)e * D_ + nb * 128 + r) * I_ + cswz * 8;
        ldsA[i] = w * 2048 + i * 512;
    }
    f32x4 acc[4][4];
    const f32x4 fz = {0.f, 0.f, 0.f, 0.f};
    #pragma unroll
    for (int m = 0; m < 4; ++m)
        #pragma unroll
        for (int n = 0; n < 4; ++n) acc[m][n] = fz;
    for (int ks = 0; ks < 8; ++ks) {
        __syncthreads();
        int ko = ks * 64;
        #pragma unroll
        for (int i = 0; i < 4; ++i) {
            gload16(h + aofs[i] + ko, &Als[ldsA[i]]);
            gload16(w2h + bofs[i] + ko, &Bs[ldsA[i]]);
        }
        __syncthreads();
        #pragma unroll
        for (int kk = 0; kk < 2; ++kk) {
            f16x8 af[4], bf[4];
            int kb = kk * 32 + (lane >> 4) * 8;
            #pragma unroll
            for (int m = 0; m < 4; ++m) {
                int row = wr * 64 + m * 16 + (lane & 15);
                af[m] = *(const f16x8*)&Als[row * 64 + (kb ^ ((row & 7) * 8))];
            }
            #pragma unroll
            for (int n = 0; n < 4; ++n) {
                int row = wc * 64 + n * 16 + (lane & 15);
                bf[n] = *(const f16x8*)&Bs[row * 64 + (kb ^ ((row & 7) * 8))];
            }
            #pragma unroll
            for (int m = 0; m < 4; ++m)
                #pragma unroll
                for (int n = 0; n < 4; ++n)
                    acc[m][n] = __builtin_amdgcn_mfma_f32_16x16x32_f16(af[m], bf[n], acc[m][n], 0, 0, 0);
        }
    }
    int dcb = nb * 128 + wc * 64;
    float bias[4];
    #pragma unroll
    for (int n = 0; n < 4; ++n) bias[n] = b2[e * D_ + dcb + n * 16 + (lane & 15)];
    #pragma unroll
    for (int m = 0; m < 4; ++m)
        #pragma unroll
        for (int r = 0; r < 4; ++r) {
            int re = mb * 128 + wr * 64 + m * 16 + (lane >> 4) * 4 + r;
            int bb = re >> 9;
            int pos = bb * TPB_ + e * 512 + (re & 511);
            int tokk = src_tok[pos];
            float g = 0.f;
            #pragma unroll
            for (int k = 0; k < K_; ++k)
                if (invp[bb * TPB_ + tokk * K_ + k] == e * 512 + (re & 511))
                    g = ts[bb * TPB_ + tokk * K_ + k];
            float* op = out + ((size_t)(bb * S_ + tokk)) * D_;
            #pragma unroll
            for (int n = 0; n < 4; ++n) {
                int col = dcb + n * 16 + (lane & 15);
                atomicAdd(op + col, g * (acc[m][n][r] + bias[n]));
            }
        }
}

// ---------------- combine: out[b,s,:] = sum_k ts * h2p[pos(b,s,k)] -----------
__global__ __launch_bounds__(256) void k_combine(
    const f16* __restrict__ h2p, const float* __restrict__ ts,
    const int* __restrict__ invp, float* __restrict__ out) {
    int w = threadIdx.x >> 6, lane = threadIdx.x & 63;
    int t = blockIdx.x * 4 + w;
    int b = t >> 11, s = t & 2047;
    int base = b * TPB_ + s * 4;
    float g[4]; const f16* rows[4];
    #pragma unroll
    for (int k = 0; k < 4; ++k) {
        int p = invp[base + k];
        g[k] = ts[base + k];
        int e = p >> 9, n = (b << 9) + (p & 511);
        rows[k] = h2p + ((size_t)(e * EROWS_ + n)) * D_;
    }
    float* op = out + (size_t)t * D_;
    #pragma unroll
    for (int c = 0; c < 2; ++c) {
        int d = c * 512 + lane * 8;
        float a[8] = {0.f};
        #pragma unroll
        for (int k = 0; k < 4; ++k) {
            f16x8 v = *(const f16x8*)(rows[k] + d);
            #pragma unroll
            for (int j = 0; j < 8; ++j) a[j] += g[k] * (float)v[j];
        }
        *(float4*)(op + d)     = make_float4(a[0], a[1], a[2], a[3]);
        *(float4*)(op + d + 4) = make_float4(a[4], a[5], a[6], a[7]);
    }
}

// ---------------- launch -----------------------------------------------------
extern "C" void kernel_launch(void* const* d_in, const int* in_sizes, int n_in,
                              void* d_out, int out_size, void* d_ws, size_t ws_size,
                              hipStream_t stream) {
    const float* x  = (const float*)d_in[0];
    const float* rw = (const float*)d_in[1];
    const float* w1 = (const float*)d_in[2];
    const float* b1 = (const float*)d_in[3];
    const float* w2 = (const float*)d_in[4];
    const float* b2 = (const float*)d_in[5];
    const float* w3 = (const float*)d_in[6];
    const float* b3 = (const float*)d_in[7];
    float* out = (float*)d_out;

    const size_t NEL = (size_t)B_ * S_ * D_;
    char* p = (char*)d_ws;
    f16* xh  = (f16*)p; p += NEL * 2;
    f16* w1h = (f16*)p; p += NEL * 2;
    f16* w3h = (f16*)p; p += NEL * 2;
    f16* w2h = (f16*)p; p += NEL * 2;
    f16* h   = (f16*)p; p += (size_t)E_ * EROWS_ * I_ * 2;
    int*   sel     = (int*)p;   p += (size_t)B_ * TPB_ * 4;
    float* ts      = (float*)p; p += (size_t)B_ * TPB_ * 4;
    int*   src_tok = (int*)p;   p += (size_t)B_ * TPB_ * 4;
    int*   invp    = (int*)p;   p += (size_t)B_ * TPB_ * 4;
    f16* h2p = (f16*)p; p += (size_t)E_ * EROWS_ * D_ * 2;
    size_t need = (size_t)(p - (char*)d_ws);

    k_convert<<<2048, 256, 0, stream>>>(w1, w3, w2, w1h, w3h, w2h);
    k_router<<<2048, 256, 0, stream>>>(x, rw, xh, sel, ts);
    k_sort<<<4, 1024, 0, stream>>>(sel, src_tok, invp);
    k_gemm1<<<1024, 256, 0, stream>>>(xh, w1h, w3h, b1, b3, src_tok, h);
    if (ws_size >= need) {
        k_gemm2<<<2048, 256, 0, stream>>>(h, w2h, b2, h2p);
        k_combine<<<2048, 256, 0, stream>>>(h2p, ts, invp, out);
    } else {
        hipMemsetAsync(d_out, 0, (size_t)out_size * sizeof(float), stream);
        k_gemm2_atomic<<<2048, 256, 0, stream>>>(h, w2h, b2, src_tok, invp, ts, out);
    }
}